// Round 4
// baseline (203.974 us; speedup 1.0000x reference)
//
#include <hip/hip_runtime.h>

typedef unsigned int uint32;
typedef unsigned short ushort16;
typedef __attribute__((ext_vector_type(8))) short bf16x8;
typedef __attribute__((ext_vector_type(4))) float f32x4;
typedef __attribute__((ext_vector_type(4))) uint32 u32x4;

#define B_SZ 16384
#define MARGIN 0.04f

// ---------- bf16 helpers (manual RNE) ----------
__device__ __forceinline__ ushort16 f2bf(float f) {
  uint32 u = __float_as_uint(f);
  u += 0x7fffu + ((u >> 16) & 1u);
  return (ushort16)(u >> 16);
}
__device__ __forceinline__ float bf2f(ushort16 h) { return __uint_as_float(((uint32)h) << 16); }
__device__ __forceinline__ float bflo(uint32 u) { return __uint_as_float(u << 16); }
__device__ __forceinline__ float bfhi(uint32 u) { return __uint_as_float(u & 0xffff0000u); }
__device__ __forceinline__ uint32 pk2(float lo, float hi) {
  return ((uint32)f2bf(hi) << 16) | (uint32)f2bf(lo);
}
__device__ __forceinline__ int dot4(uint32 a, uint32 b, int c) {
#if __has_builtin(__builtin_amdgcn_sdot4)
  return __builtin_amdgcn_sdot4((int)a, (int)b, c, false);
#else
  int s = c;
#pragma unroll
  for (int k = 0; k < 4; ++k)
    s += (int)(char)(a >> (8 * k)) * (int)(char)(b >> (8 * k));
  return s;
#endif
}
__device__ __forceinline__ int q8(float v, float inv) {
  int q = (int)rintf(v * inv);
  return q > 127 ? 127 : (q < -127 ? -127 : q);
}

// ---------- prep: Wall = [Wfc^T (12) | 52 zeros | Wbin (768)] as bf16 ----------
__global__ void prep_wall(const float* __restrict__ Wfc, const float* __restrict__ Wbin,
                          ushort16* __restrict__ Wall) {
  int idx = blockIdx.x * 256 + threadIdx.x;      // 832*1024 threads
  int j = idx >> 10, n = idx & 1023;
  float v = 0.f;
  if (j < 12) v = Wfc[n * 12 + j];
  else if (j >= 64) v = Wbin[(size_t)(j - 64) * 1024 + n];
  Wall[idx] = f2bf(v);
}

// ---------- prep: Wres[c,k] (contiguous [1024][3] f32) -> int8 wq[ck][d][n] + scale ----------
__global__ __launch_bounds__(256) void prep_wres_i8(const float* __restrict__ Wres,
                                                    uint32* __restrict__ wq,
                                                    float* __restrict__ swk) {
  __shared__ float red[256];
  const int ck = blockIdx.x;                     // 768 blocks
  const int t = threadIdx.x;
  const float4* base4 = (const float4*)(Wres + (size_t)ck * 3072);
  float4 v0 = base4[3 * t], v1 = base4[3 * t + 1], v2 = base4[3 * t + 2];
  float vals[12] = {v0.x, v0.y, v0.z, v0.w, v1.x, v1.y, v1.z, v1.w, v2.x, v2.y, v2.z, v2.w};
  float m = 0.f;
#pragma unroll
  for (int i = 0; i < 12; ++i) m = fmaxf(m, fabsf(vals[i]));
  red[t] = m; __syncthreads();
  for (int s = 128; s; s >>= 1) { if (t < s) red[t] = fmaxf(red[t], red[t + s]); __syncthreads(); }
  float mx = fmaxf(red[0], 1e-20f);
  float inv = 127.f / mx;
  if (t == 0) swk[ck] = mx / 127.f;
  // thread t holds n = 4t..4t+3, d = 0..2 : vals[(n-4t)*3 + d]
#pragma unroll
  for (int d = 0; d < 3; ++d) {
    uint32 u = 0;
#pragma unroll
    for (int j = 0; j < 4; ++j)
      u |= ((uint32)(unsigned char)(char)q8(vals[j * 3 + d], inv)) << (8 * j);
    wq[((size_t)(ck * 3 + d) << 8) + t] = u;
  }
}

// ---------- prep: x -> bf16 xb + int8 xq + per-row scale ----------
__global__ __launch_bounds__(256) void xprep2(const float* __restrict__ x,
                                              uint2* __restrict__ xb,
                                              uint32* __restrict__ xq,
                                              float* __restrict__ sxb) {
  __shared__ float red[256];
  const int b = blockIdx.x;
  const int t = threadIdx.x;
  float4 v = ((const float4*)(x + (size_t)b * 1024))[t];
  uint2 o; o.x = pk2(v.x, v.y); o.y = pk2(v.z, v.w);
  xb[(size_t)b * 256 + t] = o;
  float m = fmaxf(fmaxf(fabsf(v.x), fabsf(v.y)), fmaxf(fabsf(v.z), fabsf(v.w)));
  red[t] = m; __syncthreads();
  for (int s = 128; s; s >>= 1) { if (t < s) red[t] = fmaxf(red[t], red[t + s]); __syncthreads(); }
  float mx = fmaxf(red[0], 1e-20f);
  float inv = 127.f / mx;
  if (t == 0) sxb[b] = mx / 127.f;
  uint32 u = ((uint32)(unsigned char)(char)q8(v.x, inv)) |
             ((uint32)(unsigned char)(char)q8(v.y, inv)) << 8 |
             ((uint32)(unsigned char)(char)q8(v.z, inv)) << 16 |
             ((uint32)(unsigned char)(char)q8(v.w, inv)) << 24;
  xq[(size_t)b * 256 + t] = u;
}

// ---------- legacy preps for fallback path ----------
__global__ void prep_wres(const float* __restrict__ Wres, ushort16* __restrict__ Wres_b) {
  int idx = blockIdx.x * 256 + threadIdx.x;
  int n = idx & 1023;
  int d = (idx >> 10) % 3;
  int ck = idx / 3072;
  Wres_b[idx] = f2bf(Wres[((size_t)ck * 1024 + n) * 3 + d]);
}

// ---------- MFMA GEMM: [16384 x 832] = xb @ Wall^T, fused y0/ybin epilogue ----------
template<int XB>
__global__ __launch_bounds__(256) void gemm_mfma(
    const float* __restrict__ x, const ushort16* __restrict__ xb,
    const float* __restrict__ bfc, const float* __restrict__ bbin,
    const ushort16* __restrict__ Wall, ushort16* __restrict__ ybin,
    float* __restrict__ out) {
  __shared__ __align__(16) char smem[24576];     // A: 16384 B, B: 8192 B
  const int t = threadIdx.x;
  const int lane = t & 63, wid = t >> 6;
  const int wm = wid & 1, wn = wid >> 1;

  int orig = blockIdx.x;
  int bid = (orig & 7) * 208 + (orig >> 3);      // XCD-bijective (1664 = 8*208)
  int nb = bid % 13, mb = bid / 13;
  const int b0 = mb * 128;

  f32x4 acc[4][2];
#pragma unroll
  for (int i = 0; i < 4; ++i)
#pragma unroll
    for (int j = 0; j < 2; ++j) acc[i][j] = (f32x4){0.f, 0.f, 0.f, 0.f};

  const int lr = lane & 15, lq = lane >> 4;
  const int fxor = (lr & 7) << 4;
  const int gs = (lane & 7) ^ (lane >> 3);
  const int grw = lane >> 3;

  for (int kc = 0; kc < 1024; kc += 64) {
    __syncthreads();
    if (XB) {
#pragma unroll
      for (int i = 0; i < 4; ++i) {
        int chunk = i * 4 + wid;
        int row = chunk * 8 + grw;
        const ushort16* src = xb + (size_t)(b0 + row) * 1024 + kc + gs * 8;
        __builtin_amdgcn_global_load_lds(
            (const __attribute__((address_space(1))) uint32*)src,
            (__attribute__((address_space(3))) uint32*)(smem + chunk * 1024), 16, 0, 0);
      }
#pragma unroll
      for (int i = 0; i < 2; ++i) {
        int chunk = i * 4 + wid;
        int row = chunk * 8 + grw;
        const ushort16* src = Wall + (size_t)(nb * 64 + row) * 1024 + kc + gs * 8;
        __builtin_amdgcn_global_load_lds(
            (const __attribute__((address_space(1))) uint32*)src,
            (__attribute__((address_space(3))) uint32*)(smem + 16384 + chunk * 1024), 16, 0, 0);
      }
    } else {
      const int sxor = ((t >> 3) & 7) << 4;
#pragma unroll
      for (int i = 0; i < 4; ++i) {
        int s = t + i * 256;
        int row = s >> 3, c8 = (s & 7) * 8;
        int dst = row * 128 + ((c8 * 2) ^ sxor);
        const float4* src = (const float4*)(x + (size_t)(b0 + row) * 1024 + kc + c8);
        float4 v0 = src[0], v1 = src[1];
        u32x4 pv;
        pv.x = pk2(v0.x, v0.y); pv.y = pk2(v0.z, v0.w);
        pv.z = pk2(v1.x, v1.y); pv.w = pk2(v1.z, v1.w);
        *(u32x4*)(smem + dst) = pv;
      }
#pragma unroll
      for (int i = 0; i < 2; ++i) {
        int s = t + i * 256;
        int row = s >> 3, c8 = (s & 7) * 8;
        int dst = 16384 + row * 128 + ((c8 * 2) ^ sxor);
        u32x4 v = *(const u32x4*)(Wall + (size_t)(nb * 64 + row) * 1024 + kc + c8);
        *(u32x4*)(smem + dst) = v;
      }
    }
    __syncthreads();
#pragma unroll
    for (int kk = 0; kk < 2; ++kk) {
      int cbx = (kk * 64 + lq * 16) ^ fxor;
      bf16x8 af[4], bfr[2];
#pragma unroll
      for (int i = 0; i < 4; ++i) {
        int row = wm * 64 + i * 16 + lr;
        af[i] = *(const bf16x8*)(smem + row * 128 + cbx);
      }
#pragma unroll
      for (int j = 0; j < 2; ++j) {
        int row = wn * 32 + j * 16 + lr;
        bfr[j] = *(const bf16x8*)(smem + 16384 + row * 128 + cbx);
      }
#pragma unroll
      for (int i = 0; i < 4; ++i)
#pragma unroll
        for (int j = 0; j < 2; ++j)
          acc[i][j] = __builtin_amdgcn_mfma_f32_16x16x32_bf16(af[i], bfr[j], acc[i][j], 0, 0, 0);
    }
  }

#pragma unroll
  for (int i = 0; i < 4; ++i)
#pragma unroll
    for (int j = 0; j < 2; ++j)
#pragma unroll
      for (int r = 0; r < 4; ++r) {
        int gm = b0 + wm * 64 + i * 16 + lq * 4 + r;
        int col = wn * 32 + j * 16 + lr;
        float val = acc[i][j][r];
        if (nb == 0) {
          if (col < 12) out[(size_t)gm * 12 + col] = val + bfc[col];
        } else {
          int c = nb - 1;
          ybin[((size_t)gm * 12 + c) * 64 + col] = f2bf(val + bbin[c * 64 + col]);
        }
      }
}

// ---------- select3: per-b block, int8 residual dot via sdot4 ----------
__global__ __launch_bounds__(256) void select3(
    const float* __restrict__ x, const float* __restrict__ Wbin,
    const float* __restrict__ bbin, const float* __restrict__ bres,
    const float* __restrict__ centers, const uint32* __restrict__ wq,
    const float* __restrict__ swk, const uint32* __restrict__ xq,
    const float* __restrict__ sxb, const ushort16* __restrict__ ybin,
    float* __restrict__ out) {
  const int lane = threadIdx.x & 63;
  const int w = threadIdx.x >> 6;
  const int b = blockIdx.x;

  const u32x4 xi = *(const u32x4*)(xq + (size_t)b * 256 + lane * 4);   // 16 int8 of x
  const float sx = sxb[b];
  const size_t obase = (size_t)B_SZ * 12 + (size_t)b * 36;

#pragma unroll 1
  for (int cc = 0; cc < 3; ++cc) {
    const int c = w * 3 + cc;
    float v = bf2f(ybin[((size_t)b * 12 + c) * 64 + lane]);
    // wave-wide top-2 butterfly; ties -> smaller k (first-max)
    float m1 = v, m2 = -3.4e38f;
    int k1 = lane;
    for (int off = 32; off; off >>= 1) {
      float om1 = __shfl_xor(m1, off);
      int   ok1 = __shfl_xor(k1, off);
      float om2 = __shfl_xor(m2, off);
      bool take = (om1 > m1) || (om1 == m1 && ok1 < k1);
      float lose = take ? m1 : om1;
      m2 = fmaxf(fmaxf(m2, om2), lose);
      if (take) { m1 = om1; k1 = ok1; }
    }
    int ind = k1;
    if (m1 - m2 <= MARGIN) {            // wave-uniform rescue branch
      float xv[16];
      const float4* xr = (const float4*)(x + (size_t)b * 1024 + lane * 16);
#pragma unroll
      for (int q = 0; q < 4; ++q) {
        float4 vv = xr[q];
        xv[4 * q] = vv.x; xv[4 * q + 1] = vv.y; xv[4 * q + 2] = vv.z; xv[4 * q + 3] = vv.w;
      }
      unsigned long long mask = __ballot(v >= m1 - MARGIN);
      double best = -1.0e300;
      int bk = 0;
      while (mask) {
        int k = __ffsll(mask) - 1;
        mask &= (mask - 1);
        const float4* wr4 = (const float4*)(Wbin + ((size_t)c * 64 + k) * 1024 + lane * 16);
        double s = 0.0;
#pragma unroll
        for (int q = 0; q < 4; ++q) {
          float4 wv = wr4[q];
          s += (double)xv[4 * q] * (double)wv.x + (double)xv[4 * q + 1] * (double)wv.y +
               (double)xv[4 * q + 2] * (double)wv.z + (double)xv[4 * q + 3] * (double)wv.w;
        }
        for (int off = 32; off; off >>= 1) s += __shfl_xor(s, off);
        s += (double)bbin[c * 64 + k];
        if (s > best) { best = s; bk = k; }   // ascending k + strict > = first-max
      }
      ind = bk;
    }
    const int ck = c * 64 + ind;
    // int8 residual dot: 4 sdot4 per d
    const uint32* wr = wq + ((size_t)ck * 3) * 256;
    int acc[3];
#pragma unroll
    for (int d = 0; d < 3; ++d) {
      u32x4 wv = *(const u32x4*)(wr + d * 256 + lane * 4);
      int s = dot4(xi.x, wv.x, 0);
      s = dot4(xi.y, wv.y, s);
      s = dot4(xi.z, wv.z, s);
      acc[d] = dot4(xi.w, wv.w, s);
    }
    for (int off = 32; off; off >>= 1) {
      acc[0] += __shfl_xor(acc[0], off);
      acc[1] += __shfl_xor(acc[1], off);
      acc[2] += __shfl_xor(acc[2], off);
    }
    if (lane == 0) {
      float sc = sx * swk[ck];
      out[obase + 0 * 12 + c] = centers[ind * 3 + 0] + bres[ck * 3 + 0] + sc * (float)acc[0];
      out[obase + 1 * 12 + c] = centers[ind * 3 + 1] + bres[ck * 3 + 1] + sc * (float)acc[1];
      out[obase + 2 * 12 + c] = centers[ind * 3 + 2] + bres[ck * 3 + 2] + sc * (float)acc[2];
    }
  }
}

// ---------- fallback select (R3-validated, bf16 Wres_b, f32 x) ----------
__global__ __launch_bounds__(256) void select2(
    const float* __restrict__ x, const float* __restrict__ Wbin,
    const float* __restrict__ bbin, const float* __restrict__ bres,
    const float* __restrict__ centers, const ushort16* __restrict__ Wres_b,
    const ushort16* __restrict__ ybin, float* __restrict__ out) {
  const int lane = threadIdx.x & 63;
  const int w = threadIdx.x >> 6;
  const int b = blockIdx.x;
  float xv[16];
  {
    const float4* xr = (const float4*)(x + (size_t)b * 1024 + lane * 16);
#pragma unroll
    for (int q = 0; q < 4; ++q) {
      float4 v = xr[q];
      xv[4 * q] = v.x; xv[4 * q + 1] = v.y; xv[4 * q + 2] = v.z; xv[4 * q + 3] = v.w;
    }
  }
  const size_t obase = (size_t)B_SZ * 12 + (size_t)b * 36;
#pragma unroll 1
  for (int cc = 0; cc < 3; ++cc) {
    const int c = w * 3 + cc;
    float v = bf2f(ybin[((size_t)b * 12 + c) * 64 + lane]);
    float m1 = v, m2 = -3.4e38f;
    int k1 = lane;
    for (int off = 32; off; off >>= 1) {
      float om1 = __shfl_xor(m1, off);
      int   ok1 = __shfl_xor(k1, off);
      float om2 = __shfl_xor(m2, off);
      bool take = (om1 > m1) || (om1 == m1 && ok1 < k1);
      float lose = take ? m1 : om1;
      m2 = fmaxf(fmaxf(m2, om2), lose);
      if (take) { m1 = om1; k1 = ok1; }
    }
    int ind = k1;
    if (m1 - m2 <= MARGIN) {
      unsigned long long mask = __ballot(v >= m1 - MARGIN);
      double best = -1.0e300;
      int bk = 0;
      while (mask) {
        int k = __ffsll(mask) - 1;
        mask &= (mask - 1);
        const float4* wr4 = (const float4*)(Wbin + ((size_t)c * 64 + k) * 1024 + lane * 16);
        double s = 0.0;
#pragma unroll
        for (int q = 0; q < 4; ++q) {
          float4 wv = wr4[q];
          s += (double)xv[4 * q] * (double)wv.x + (double)xv[4 * q + 1] * (double)wv.y +
               (double)xv[4 * q + 2] * (double)wv.z + (double)xv[4 * q + 3] * (double)wv.w;
        }
        for (int off = 32; off; off >>= 1) s += __shfl_xor(s, off);
        s += (double)bbin[c * 64 + k];
        if (s > best) { best = s; bk = k; }
      }
      ind = bk;
    }
    const ushort16* wr = Wres_b + ((size_t)(c * 64 + ind) * 3) * 1024;
    float a[3] = {0.f, 0.f, 0.f};
#pragma unroll
    for (int d = 0; d < 3; ++d) {
      const u32x4* p = (const u32x4*)(wr + d * 1024 + lane * 16);
      u32x4 w0 = p[0], w1 = p[1];
      uint32 uw[8] = {w0.x, w0.y, w0.z, w0.w, w1.x, w1.y, w1.z, w1.w};
#pragma unroll
      for (int q = 0; q < 8; ++q) {
        a[d] = fmaf(xv[2 * q],     bflo(uw[q]), a[d]);
        a[d] = fmaf(xv[2 * q + 1], bfhi(uw[q]), a[d]);
      }
    }
    for (int off = 32; off; off >>= 1) {
      a[0] += __shfl_xor(a[0], off);
      a[1] += __shfl_xor(a[1], off);
      a[2] += __shfl_xor(a[2], off);
    }
    if (lane == 0) {
      int ck = c * 64 + ind;
      out[obase + 0 * 12 + c] = centers[ind * 3 + 0] + bres[ck * 3 + 0] + a[0];
      out[obase + 1 * 12 + c] = centers[ind * 3 + 1] + bres[ck * 3 + 1] + a[1];
      out[obase + 2 * 12 + c] = centers[ind * 3 + 2] + bres[ck * 3 + 2] + a[2];
    }
  }
}

extern "C" void kernel_launch(void* const* d_in, const int* in_sizes, int n_in,
                              void* d_out, int out_size, void* d_ws, size_t ws_size,
                              hipStream_t stream) {
  const float* x       = (const float*)d_in[0];
  const float* Wfc     = (const float*)d_in[1];
  const float* bfc     = (const float*)d_in[2];
  const float* Wbin    = (const float*)d_in[3];
  const float* bbin    = (const float*)d_in[4];
  const float* Wres    = (const float*)d_in[5];
  const float* bres    = (const float*)d_in[6];
  const float* centers = (const float*)d_in[7];
  float* out = (float*)d_out;

  char* ws = (char*)d_ws;
  ushort16* Wall = (ushort16*)ws;                              // 1,703,936 B
  if (ws_size >= 79629312ull) {
    // fast path layout
    uint32*   wq   = (uint32*)(ws + 1703936);                  // 2,359,296 B
    float*    swk  = (float*)(ws + 4063232);                   // 3,072 B (+pad)
    ushort16* ybin = (ushort16*)(ws + 4066304);                // 25,165,824 B
    ushort16* xb   = (ushort16*)(ws + 29232128);               // 33,554,432 B
    uint32*   xq   = (uint32*)(ws + 62786560);                 // 16,777,216 B
    float*    sxb  = (float*)(ws + 79563776);                  // 65,536 B -> end 79,629,312

    prep_wall<<<3328, 256, 0, stream>>>(Wfc, Wbin, Wall);
    prep_wres_i8<<<768, 256, 0, stream>>>(Wres, wq, swk);
    xprep2<<<16384, 256, 0, stream>>>(x, (uint2*)xb, xq, sxb);
    gemm_mfma<1><<<1664, 256, 0, stream>>>(x, xb, bfc, bbin, Wall, ybin, out);
    select3<<<B_SZ, 256, 0, stream>>>(x, Wbin, bbin, bres, centers,
                                      wq, swk, xq, sxb, ybin, out);
  } else {
    // R3-validated fallback
    ushort16* Wres_b = (ushort16*)(ws + 1703936);              // 4,718,592 B
    ushort16* ybin   = (ushort16*)(ws + 6422528);              // 25,165,824 B
    prep_wall<<<3328, 256, 0, stream>>>(Wfc, Wbin, Wall);
    prep_wres<<<9216, 256, 0, stream>>>(Wres, Wres_b);
    gemm_mfma<0><<<1664, 256, 0, stream>>>(x, (const ushort16*)ws, bfc, bbin, Wall, ybin, out);
    select2<<<B_SZ, 256, 0, stream>>>(x, Wbin, bbin, bres, centers, Wres_b, ybin, out);
  }
}

// Round 5
// 180.330 us; speedup vs baseline: 1.1311x; 1.1311x over previous
//
#include <hip/hip_runtime.h>

typedef unsigned int uint32;
typedef unsigned short ushort16;
typedef __attribute__((ext_vector_type(8))) short bf16x8;
typedef __attribute__((ext_vector_type(4))) float f32x4;
typedef __attribute__((ext_vector_type(4))) uint32 u32x4;

#define B_SZ 16384
#define MARGIN 0.04f

// ---------- bf16 helpers (manual RNE) ----------
__device__ __forceinline__ ushort16 f2bf(float f) {
  uint32 u = __float_as_uint(f);
  u += 0x7fffu + ((u >> 16) & 1u);
  return (ushort16)(u >> 16);
}
__device__ __forceinline__ float bf2f(ushort16 h) { return __uint_as_float(((uint32)h) << 16); }
__device__ __forceinline__ float bflo(uint32 u) { return __uint_as_float(u << 16); }
__device__ __forceinline__ float bfhi(uint32 u) { return __uint_as_float(u & 0xffff0000u); }
__device__ __forceinline__ uint32 pk2(float lo, float hi) {
  return ((uint32)f2bf(hi) << 16) | (uint32)f2bf(lo);
}
__device__ __forceinline__ int dot4(uint32 a, uint32 b, int c) {
#if __has_builtin(__builtin_amdgcn_sdot4)
  return __builtin_amdgcn_sdot4((int)a, (int)b, c, false);
#else
  int s = c;
#pragma unroll
  for (int k = 0; k < 4; ++k)
    s += (int)(char)(a >> (8 * k)) * (int)(char)(b >> (8 * k));
  return s;
#endif
}
__device__ __forceinline__ int q8(float v, float inv) {
  int q = (int)rintf(v * inv);
  return q > 127 ? 127 : (q < -127 ? -127 : q);
}

// ---------- prep: Wall = [Wfc^T (12) | 52 zeros | Wbin (768)] as bf16 ----------
__global__ void prep_wall(const float* __restrict__ Wfc, const float* __restrict__ Wbin,
                          ushort16* __restrict__ Wall) {
  int idx = blockIdx.x * 256 + threadIdx.x;      // 832*1024 threads
  int j = idx >> 10, n = idx & 1023;
  float v = 0.f;
  if (j < 12) v = Wfc[n * 12 + j];
  else if (j >= 64) v = Wbin[(size_t)(j - 64) * 1024 + n];
  Wall[idx] = f2bf(v);
}

// ---------- prep: Wres[c,k] -> int8 wq[ck][d][n] + scale ----------
__global__ __launch_bounds__(256) void prep_wres_i8(const float* __restrict__ Wres,
                                                    uint32* __restrict__ wq,
                                                    float* __restrict__ swk) {
  __shared__ float red[256];
  const int ck = blockIdx.x;                     // 768 blocks
  const int t = threadIdx.x;
  const float4* base4 = (const float4*)(Wres + (size_t)ck * 3072);
  float4 v0 = base4[3 * t], v1 = base4[3 * t + 1], v2 = base4[3 * t + 2];
  float vals[12] = {v0.x, v0.y, v0.z, v0.w, v1.x, v1.y, v1.z, v1.w, v2.x, v2.y, v2.z, v2.w};
  float m = 0.f;
#pragma unroll
  for (int i = 0; i < 12; ++i) m = fmaxf(m, fabsf(vals[i]));
  red[t] = m; __syncthreads();
  for (int s = 128; s; s >>= 1) { if (t < s) red[t] = fmaxf(red[t], red[t + s]); __syncthreads(); }
  float mx = fmaxf(red[0], 1e-20f);
  float inv = 127.f / mx;
  if (t == 0) swk[ck] = mx / 127.f;
#pragma unroll
  for (int d = 0; d < 3; ++d) {
    uint32 u = 0;
#pragma unroll
    for (int j = 0; j < 4; ++j)
      u |= ((uint32)(unsigned char)(char)q8(vals[j * 3 + d], inv)) << (8 * j);
    wq[((size_t)(ck * 3 + d) << 8) + t] = u;
  }
}

// ---------- prep: x -> bf16 xb + int8 xq + per-row scale ----------
__global__ __launch_bounds__(256) void xprep2(const float* __restrict__ x,
                                              uint2* __restrict__ xb,
                                              uint32* __restrict__ xq,
                                              float* __restrict__ sxb) {
  __shared__ float red[256];
  const int b = blockIdx.x;
  const int t = threadIdx.x;
  float4 v = ((const float4*)(x + (size_t)b * 1024))[t];
  uint2 o; o.x = pk2(v.x, v.y); o.y = pk2(v.z, v.w);
  xb[(size_t)b * 256 + t] = o;
  float m = fmaxf(fmaxf(fabsf(v.x), fabsf(v.y)), fmaxf(fabsf(v.z), fabsf(v.w)));
  red[t] = m; __syncthreads();
  for (int s = 128; s; s >>= 1) { if (t < s) red[t] = fmaxf(red[t], red[t + s]); __syncthreads(); }
  float mx = fmaxf(red[0], 1e-20f);
  float inv = 127.f / mx;
  if (t == 0) sxb[b] = mx / 127.f;
  uint32 u = ((uint32)(unsigned char)(char)q8(v.x, inv)) |
             ((uint32)(unsigned char)(char)q8(v.y, inv)) << 8 |
             ((uint32)(unsigned char)(char)q8(v.z, inv)) << 16 |
             ((uint32)(unsigned char)(char)q8(v.w, inv)) << 24;
  xq[(size_t)b * 256 + t] = u;
}

// ---------- legacy prep for fallback path ----------
__global__ void prep_wres(const float* __restrict__ Wres, ushort16* __restrict__ Wres_b) {
  int idx = blockIdx.x * 256 + threadIdx.x;
  int n = idx & 1023;
  int d = (idx >> 10) % 3;
  int ck = idx / 3072;
  Wres_b[idx] = f2bf(Wres[((size_t)ck * 1024 + n) * 3 + d]);
}

// ---------- MFMA GEMM: [16384 x 832] = xb @ Wall^T, fused y0/ybin epilogue ----------
template<int XB>
__global__ __launch_bounds__(256) void gemm_mfma(
    const float* __restrict__ x, const ushort16* __restrict__ xb,
    const float* __restrict__ bfc, const float* __restrict__ bbin,
    const ushort16* __restrict__ Wall, ushort16* __restrict__ ybin,
    float* __restrict__ out) {
  __shared__ __align__(16) char smem[24576];     // A: 16384 B, B: 8192 B
  const int t = threadIdx.x;
  const int lane = t & 63, wid = t >> 6;
  const int wm = wid & 1, wn = wid >> 1;

  int orig = blockIdx.x;
  int bid = (orig & 7) * 208 + (orig >> 3);      // XCD-bijective (1664 = 8*208)
  int nb = bid % 13, mb = bid / 13;
  const int b0 = mb * 128;

  f32x4 acc[4][2];
#pragma unroll
  for (int i = 0; i < 4; ++i)
#pragma unroll
    for (int j = 0; j < 2; ++j) acc[i][j] = (f32x4){0.f, 0.f, 0.f, 0.f};

  const int lr = lane & 15, lq = lane >> 4;
  const int fxor = (lr & 7) << 4;
  const int gs = (lane & 7) ^ (lane >> 3);
  const int grw = lane >> 3;

  for (int kc = 0; kc < 1024; kc += 64) {
    __syncthreads();
    if (XB) {
#pragma unroll
      for (int i = 0; i < 4; ++i) {
        int chunk = i * 4 + wid;
        int row = chunk * 8 + grw;
        const ushort16* src = xb + (size_t)(b0 + row) * 1024 + kc + gs * 8;
        __builtin_amdgcn_global_load_lds(
            (const __attribute__((address_space(1))) uint32*)src,
            (__attribute__((address_space(3))) uint32*)(smem + chunk * 1024), 16, 0, 0);
      }
#pragma unroll
      for (int i = 0; i < 2; ++i) {
        int chunk = i * 4 + wid;
        int row = chunk * 8 + grw;
        const ushort16* src = Wall + (size_t)(nb * 64 + row) * 1024 + kc + gs * 8;
        __builtin_amdgcn_global_load_lds(
            (const __attribute__((address_space(1))) uint32*)src,
            (__attribute__((address_space(3))) uint32*)(smem + 16384 + chunk * 1024), 16, 0, 0);
      }
    } else {
      const int sxor = ((t >> 3) & 7) << 4;
#pragma unroll
      for (int i = 0; i < 4; ++i) {
        int s = t + i * 256;
        int row = s >> 3, c8 = (s & 7) * 8;
        int dst = row * 128 + ((c8 * 2) ^ sxor);
        const float4* src = (const float4*)(x + (size_t)(b0 + row) * 1024 + kc + c8);
        float4 v0 = src[0], v1 = src[1];
        u32x4 pv;
        pv.x = pk2(v0.x, v0.y); pv.y = pk2(v0.z, v0.w);
        pv.z = pk2(v1.x, v1.y); pv.w = pk2(v1.z, v1.w);
        *(u32x4*)(smem + dst) = pv;
      }
#pragma unroll
      for (int i = 0; i < 2; ++i) {
        int s = t + i * 256;
        int row = s >> 3, c8 = (s & 7) * 8;
        int dst = 16384 + row * 128 + ((c8 * 2) ^ sxor);
        u32x4 v = *(const u32x4*)(Wall + (size_t)(nb * 64 + row) * 1024 + kc + c8);
        *(u32x4*)(smem + dst) = v;
      }
    }
    __syncthreads();
#pragma unroll
    for (int kk = 0; kk < 2; ++kk) {
      int cbx = (kk * 64 + lq * 16) ^ fxor;
      bf16x8 af[4], bfr[2];
#pragma unroll
      for (int i = 0; i < 4; ++i) {
        int row = wm * 64 + i * 16 + lr;
        af[i] = *(const bf16x8*)(smem + row * 128 + cbx);
      }
#pragma unroll
      for (int j = 0; j < 2; ++j) {
        int row = wn * 32 + j * 16 + lr;
        bfr[j] = *(const bf16x8*)(smem + 16384 + row * 128 + cbx);
      }
#pragma unroll
      for (int i = 0; i < 4; ++i)
#pragma unroll
        for (int j = 0; j < 2; ++j)
          acc[i][j] = __builtin_amdgcn_mfma_f32_16x16x32_bf16(af[i], bfr[j], acc[i][j], 0, 0, 0);
    }
  }

#pragma unroll
  for (int i = 0; i < 4; ++i)
#pragma unroll
    for (int j = 0; j < 2; ++j)
#pragma unroll
      for (int r = 0; r < 4; ++r) {
        int gm = b0 + wm * 64 + i * 16 + lq * 4 + r;
        int col = wn * 32 + j * 16 + lr;
        float val = acc[i][j][r];
        if (nb == 0) {
          if (col < 12) out[(size_t)gm * 12 + col] = val + bfc[col];
        } else {
          int c = nb - 1;
          ybin[((size_t)gm * 12 + c) * 64 + col] = f2bf(val + bbin[c * 64 + col]);
        }
      }
}

// ---------- A: thread-per-pair argmax; ind8 = ind | flag<<7 ----------
__global__ __launch_bounds__(256) void argmax_k(const ushort16* __restrict__ ybin,
                                                unsigned char* __restrict__ ind8) {
  int p = blockIdx.x * 256 + threadIdx.x;        // 768 blocks -> 196608 pairs
  const u32x4* row = (const u32x4*)(ybin + (size_t)p * 64);
  u32x4 r0 = row[0], r1 = row[1], r2 = row[2], r3 = row[3];
  u32x4 r4 = row[4], r5 = row[5], r6 = row[6], r7 = row[7];
  uint32 u[32] = {r0.x, r0.y, r0.z, r0.w, r1.x, r1.y, r1.z, r1.w,
                  r2.x, r2.y, r2.z, r2.w, r3.x, r3.y, r3.z, r3.w,
                  r4.x, r4.y, r4.z, r4.w, r5.x, r5.y, r5.z, r5.w,
                  r6.x, r6.y, r6.z, r6.w, r7.x, r7.y, r7.z, r7.w};
  float m1 = -3.4e38f, m2 = -3.4e38f;
  int k1 = 0;
#pragma unroll
  for (int j = 0; j < 32; ++j) {
    float v0 = bflo(u[j]), v1 = bfhi(u[j]);
    if (v0 > m1) { m2 = m1; m1 = v0; k1 = 2 * j; } else if (v0 > m2) m2 = v0;
    if (v1 > m1) { m2 = m1; m1 = v1; k1 = 2 * j + 1; } else if (v1 > m2) m2 = v1;
  }
  ind8[p] = (unsigned char)(k1 | ((m1 - m2 <= MARGIN) ? 128 : 0));
}

// ---------- B: per-b block, 3 classes/wave interleaved, int8 dot ----------
__global__ __launch_bounds__(256) void gather_k(
    const uint32* __restrict__ xq, const float* __restrict__ sxb,
    const unsigned char* __restrict__ ind8, const uint32* __restrict__ wq,
    const float* __restrict__ swk, const float* __restrict__ bres,
    const float* __restrict__ centers, float* __restrict__ out) {
  const int lane = threadIdx.x & 63;
  const int w = threadIdx.x >> 6;
  const int b = blockIdx.x;

  const u32x4 xi = *(const u32x4*)(xq + (size_t)b * 256 + lane * 4);
  const float sx = sxb[b];
  const size_t obase = (size_t)B_SZ * 12 + (size_t)b * 36;

  int ind[3], ck[3];
  u32x4 wv[3][3];
#pragma unroll
  for (int cc = 0; cc < 3; ++cc) {
    int c = w * 3 + cc;
    ind[cc] = ind8[b * 12 + c] & 63;
    ck[cc] = c * 64 + ind[cc];
    const uint32* wr = wq + (size_t)ck[cc] * 768;
#pragma unroll
    for (int d = 0; d < 3; ++d)
      wv[cc][d] = *(const u32x4*)(wr + d * 256 + lane * 4);
  }
  int acc[3][3];
#pragma unroll
  for (int cc = 0; cc < 3; ++cc)
#pragma unroll
    for (int d = 0; d < 3; ++d) {
      int s = dot4(xi.x, wv[cc][d].x, 0);
      s = dot4(xi.y, wv[cc][d].y, s);
      s = dot4(xi.z, wv[cc][d].z, s);
      acc[cc][d] = dot4(xi.w, wv[cc][d].w, s);
    }
  for (int off = 32; off; off >>= 1) {
#pragma unroll
    for (int cc = 0; cc < 3; ++cc)
#pragma unroll
      for (int d = 0; d < 3; ++d)
        acc[cc][d] += __shfl_xor(acc[cc][d], off);
  }
  if (lane == 0) {
#pragma unroll
    for (int cc = 0; cc < 3; ++cc) {
      int c = w * 3 + cc;
      float sc = sx * swk[ck[cc]];
      out[obase + 0 * 12 + c] = centers[ind[cc] * 3 + 0] + bres[ck[cc] * 3 + 0] + sc * (float)acc[cc][0];
      out[obase + 1 * 12 + c] = centers[ind[cc] * 3 + 1] + bres[ck[cc] * 3 + 1] + sc * (float)acc[cc][1];
      out[obase + 2 * 12 + c] = centers[ind[cc] * 3 + 2] + bres[ck[cc] * 3 + 2] + sc * (float)acc[cc][2];
    }
  }
}

// ---------- C: rescue flagged pairs with exact f64 argmax; overwrite on flip ----------
__global__ __launch_bounds__(256) void rescue_k(
    const float* __restrict__ x, const float* __restrict__ Wbin,
    const float* __restrict__ bbin, const float* __restrict__ bres,
    const float* __restrict__ centers, const unsigned char* __restrict__ ind8,
    const ushort16* __restrict__ ybin, const uint32* __restrict__ wq,
    const float* __restrict__ swk, const uint32* __restrict__ xq,
    const float* __restrict__ sxb, float* __restrict__ out) {
  const int lane = threadIdx.x & 63;
  const int w = threadIdx.x >> 6;
  const int wgid = blockIdx.x * 4 + w;           // 8192 blocks -> 32768 waves
#pragma unroll 1
  for (int i = 0; i < 6; ++i) {
    const int p = wgid + i * 32768;              // 196608 pairs total
    const int iv = ind8[p];
    if (!(iv & 128)) continue;                   // wave-uniform early out
    const int b = p / 12, c = p % 12;
    float v = bf2f(ybin[(size_t)p * 64 + lane]);
    float m1 = v;
    for (int off = 32; off; off >>= 1) m1 = fmaxf(m1, __shfl_xor(m1, off));
    unsigned long long mask = __ballot(v >= m1 - MARGIN);
    float xv[16];
    const float4* xr = (const float4*)(x + (size_t)b * 1024 + lane * 16);
#pragma unroll
    for (int q = 0; q < 4; ++q) {
      float4 vv = xr[q];
      xv[4 * q] = vv.x; xv[4 * q + 1] = vv.y; xv[4 * q + 2] = vv.z; xv[4 * q + 3] = vv.w;
    }
    double best = -1.0e300;
    int bk = 0;
    while (mask) {
      int k = __ffsll(mask) - 1;
      mask &= (mask - 1);
      const float4* wr4 = (const float4*)(Wbin + ((size_t)c * 64 + k) * 1024 + lane * 16);
      double s = 0.0;
#pragma unroll
      for (int q = 0; q < 4; ++q) {
        float4 wvv = wr4[q];
        s += (double)xv[4 * q] * (double)wvv.x + (double)xv[4 * q + 1] * (double)wvv.y +
             (double)xv[4 * q + 2] * (double)wvv.z + (double)xv[4 * q + 3] * (double)wvv.w;
      }
      for (int off = 32; off; off >>= 1) s += __shfl_xor(s, off);
      s += (double)bbin[c * 64 + k];
      if (s > best) { best = s; bk = k; }        // ascending k + strict > = first-max
    }
    if (bk != (iv & 63)) {                       // argmax flipped: recompute outputs
      const u32x4 xi = *(const u32x4*)(xq + (size_t)b * 256 + lane * 4);
      const int ckk = c * 64 + bk;
      const uint32* wr = wq + (size_t)ckk * 768;
      int acc[3];
#pragma unroll
      for (int d = 0; d < 3; ++d) {
        u32x4 wvq = *(const u32x4*)(wr + d * 256 + lane * 4);
        int s = dot4(xi.x, wvq.x, 0);
        s = dot4(xi.y, wvq.y, s);
        s = dot4(xi.z, wvq.z, s);
        acc[d] = dot4(xi.w, wvq.w, s);
      }
      for (int off = 32; off; off >>= 1) {
        acc[0] += __shfl_xor(acc[0], off);
        acc[1] += __shfl_xor(acc[1], off);
        acc[2] += __shfl_xor(acc[2], off);
      }
      if (lane == 0) {
        const size_t obase = (size_t)B_SZ * 12 + (size_t)b * 36;
        float sc = sxb[b] * swk[ckk];
        out[obase + 0 * 12 + c] = centers[bk * 3 + 0] + bres[ckk * 3 + 0] + sc * (float)acc[0];
        out[obase + 1 * 12 + c] = centers[bk * 3 + 1] + bres[ckk * 3 + 1] + sc * (float)acc[1];
        out[obase + 2 * 12 + c] = centers[bk * 3 + 2] + bres[ckk * 3 + 2] + sc * (float)acc[2];
      }
    }
  }
}

// ---------- fallback select (R3-validated, bf16 Wres_b, f32 x) ----------
__global__ __launch_bounds__(256) void select2(
    const float* __restrict__ x, const float* __restrict__ Wbin,
    const float* __restrict__ bbin, const float* __restrict__ bres,
    const float* __restrict__ centers, const ushort16* __restrict__ Wres_b,
    const ushort16* __restrict__ ybin, float* __restrict__ out) {
  const int lane = threadIdx.x & 63;
  const int w = threadIdx.x >> 6;
  const int b = blockIdx.x;
  float xv[16];
  {
    const float4* xr = (const float4*)(x + (size_t)b * 1024 + lane * 16);
#pragma unroll
    for (int q = 0; q < 4; ++q) {
      float4 v = xr[q];
      xv[4 * q] = v.x; xv[4 * q + 1] = v.y; xv[4 * q + 2] = v.z; xv[4 * q + 3] = v.w;
    }
  }
  const size_t obase = (size_t)B_SZ * 12 + (size_t)b * 36;
#pragma unroll 1
  for (int cc = 0; cc < 3; ++cc) {
    const int c = w * 3 + cc;
    float v = bf2f(ybin[((size_t)b * 12 + c) * 64 + lane]);
    float m1 = v, m2 = -3.4e38f;
    int k1 = lane;
    for (int off = 32; off; off >>= 1) {
      float om1 = __shfl_xor(m1, off);
      int   ok1 = __shfl_xor(k1, off);
      float om2 = __shfl_xor(m2, off);
      bool take = (om1 > m1) || (om1 == m1 && ok1 < k1);
      float lose = take ? m1 : om1;
      m2 = fmaxf(fmaxf(m2, om2), lose);
      if (take) { m1 = om1; k1 = ok1; }
    }
    int ind = k1;
    if (m1 - m2 <= MARGIN) {
      unsigned long long mask = __ballot(v >= m1 - MARGIN);
      double best = -1.0e300;
      int bk = 0;
      while (mask) {
        int k = __ffsll(mask) - 1;
        mask &= (mask - 1);
        const float4* wr4 = (const float4*)(Wbin + ((size_t)c * 64 + k) * 1024 + lane * 16);
        double s = 0.0;
#pragma unroll
        for (int q = 0; q < 4; ++q) {
          float4 wv = wr4[q];
          s += (double)xv[4 * q] * (double)wv.x + (double)xv[4 * q + 1] * (double)wv.y +
               (double)xv[4 * q + 2] * (double)wv.z + (double)xv[4 * q + 3] * (double)wv.w;
        }
        for (int off = 32; off; off >>= 1) s += __shfl_xor(s, off);
        s += (double)bbin[c * 64 + k];
        if (s > best) { best = s; bk = k; }
      }
      ind = bk;
    }
    const ushort16* wr = Wres_b + ((size_t)(c * 64 + ind) * 3) * 1024;
    float a[3] = {0.f, 0.f, 0.f};
#pragma unroll
    for (int d = 0; d < 3; ++d) {
      const u32x4* pp = (const u32x4*)(wr + d * 1024 + lane * 16);
      u32x4 w0 = pp[0], w1 = pp[1];
      uint32 uw[8] = {w0.x, w0.y, w0.z, w0.w, w1.x, w1.y, w1.z, w1.w};
#pragma unroll
      for (int q = 0; q < 8; ++q) {
        a[d] = fmaf(xv[2 * q],     bflo(uw[q]), a[d]);
        a[d] = fmaf(xv[2 * q + 1], bfhi(uw[q]), a[d]);
      }
    }
    for (int off = 32; off; off >>= 1) {
      a[0] += __shfl_xor(a[0], off);
      a[1] += __shfl_xor(a[1], off);
      a[2] += __shfl_xor(a[2], off);
    }
    if (lane == 0) {
      int ck = c * 64 + ind;
      out[obase + 0 * 12 + c] = centers[ind * 3 + 0] + bres[ck * 3 + 0] + a[0];
      out[obase + 1 * 12 + c] = centers[ind * 3 + 1] + bres[ck * 3 + 1] + a[1];
      out[obase + 2 * 12 + c] = centers[ind * 3 + 2] + bres[ck * 3 + 2] + a[2];
    }
  }
}

extern "C" void kernel_launch(void* const* d_in, const int* in_sizes, int n_in,
                              void* d_out, int out_size, void* d_ws, size_t ws_size,
                              hipStream_t stream) {
  const float* x       = (const float*)d_in[0];
  const float* Wfc     = (const float*)d_in[1];
  const float* bfc     = (const float*)d_in[2];
  const float* Wbin    = (const float*)d_in[3];
  const float* bbin    = (const float*)d_in[4];
  const float* Wres    = (const float*)d_in[5];
  const float* bres    = (const float*)d_in[6];
  const float* centers = (const float*)d_in[7];
  float* out = (float*)d_out;

  char* ws = (char*)d_ws;
  ushort16* Wall = (ushort16*)ws;                              // 1,703,936 B
  if (ws_size >= 79629312ull) {
    uint32*   wq   = (uint32*)(ws + 1703936);                  // 2,359,296 B
    float*    swk  = (float*)(ws + 4063232);                   // 3,072 B
    ushort16* ybin = (ushort16*)(ws + 4066304);                // 25,165,824 B
    ushort16* xb   = (ushort16*)(ws + 29232128);               // 33,554,432 B
    uint32*   xq   = (uint32*)(ws + 62786560);                 // 16,777,216 B
    float*    sxb  = (float*)(ws + 79563776);                  // 65,536 B -> end 79,629,312
    // ind8 aliases the xb region: written by argmax_k strictly AFTER gemm's last xb read
    unsigned char* ind8 = (unsigned char*)(ws + 29232128);     // 196,608 B

    prep_wall<<<3328, 256, 0, stream>>>(Wfc, Wbin, Wall);
    prep_wres_i8<<<768, 256, 0, stream>>>(Wres, wq, swk);
    xprep2<<<16384, 256, 0, stream>>>(x, (uint2*)xb, xq, sxb);
    gemm_mfma<1><<<1664, 256, 0, stream>>>(x, xb, bfc, bbin, Wall, ybin, out);
    argmax_k<<<768, 256, 0, stream>>>(ybin, ind8);
    gather_k<<<B_SZ, 256, 0, stream>>>(xq, sxb, ind8, wq, swk, bres, centers, out);
    rescue_k<<<8192, 256, 0, stream>>>(x, Wbin, bbin, bres, centers, ind8, ybin,
                                       wq, swk, xq, sxb, out);
  } else {
    // R3-validated fallback
    ushort16* Wres_b = (ushort16*)(ws + 1703936);              // 4,718,592 B
    ushort16* ybin   = (ushort16*)(ws + 6422528);              // 25,165,824 B
    prep_wall<<<3328, 256, 0, stream>>>(Wfc, Wbin, Wall);
    prep_wres<<<9216, 256, 0, stream>>>(Wres, Wres_b);
    gemm_mfma<0><<<1664, 256, 0, stream>>>(x, (const ushort16*)ws, bfc, bbin, Wall, ybin, out);
    select2<<<B_SZ, 256, 0, stream>>>(x, Wbin, bbin, bres, centers, Wres_b, ybin, out);
  }
}

// Round 6
// 167.847 us; speedup vs baseline: 1.2152x; 1.0744x over previous
//
#include <hip/hip_runtime.h>

typedef unsigned int uint32;
typedef unsigned long long uint64;
typedef unsigned short ushort16;
typedef __attribute__((ext_vector_type(8))) short bf16x8;
typedef __attribute__((ext_vector_type(4))) float f32x4;
typedef __attribute__((ext_vector_type(4))) uint32 u32x4;

#define B_SZ 16384
#define MARGIN 0.04f

// ---------- helpers ----------
__device__ __forceinline__ ushort16 f2bf(float f) {
  uint32 u = __float_as_uint(f);
  u += 0x7fffu + ((u >> 16) & 1u);
  return (ushort16)(u >> 16);
}
__device__ __forceinline__ float bf2f(ushort16 h) { return __uint_as_float(((uint32)h) << 16); }
__device__ __forceinline__ float bflo(uint32 u) { return __uint_as_float(u << 16); }
__device__ __forceinline__ float bfhi(uint32 u) { return __uint_as_float(u & 0xffff0000u); }
__device__ __forceinline__ uint32 pk2(float lo, float hi) {
  return ((uint32)f2bf(hi) << 16) | (uint32)f2bf(lo);
}
__device__ __forceinline__ int dot4(uint32 a, uint32 b, int c) {
#if __has_builtin(__builtin_amdgcn_sdot4)
  return __builtin_amdgcn_sdot4((int)a, (int)b, c, false);
#else
  int s = c;
#pragma unroll
  for (int k = 0; k < 4; ++k)
    s += (int)(char)(a >> (8 * k)) * (int)(char)(b >> (8 * k));
  return s;
#endif
}
__device__ __forceinline__ int q8(float v, float inv) {
  int q = (int)rintf(v * inv);
  return q > 127 ? 127 : (q < -127 ? -127 : q);
}

// ---------- merged prep: [0,3328) Wall | [3328,4096) Wres->i8 | [4096,20480) xprep ----------
__global__ __launch_bounds__(256) void prep_all(
    const float* __restrict__ Wfc, const float* __restrict__ Wbin,
    const float* __restrict__ Wres, const float* __restrict__ x,
    ushort16* __restrict__ Wall, uint32* __restrict__ wq, float* __restrict__ swk,
    uint2* __restrict__ xb, uint32* __restrict__ xq, float* __restrict__ sxb) {
  __shared__ float red[256];
  const int blk = blockIdx.x;
  const int t = threadIdx.x;
  if (blk < 3328) {
    int idx = blk * 256 + t;                     // 832*1024
    int j = idx >> 10, n = idx & 1023;
    float v = 0.f;
    if (j < 12) v = Wfc[n * 12 + j];
    else if (j >= 64) v = Wbin[(size_t)(j - 64) * 1024 + n];
    Wall[idx] = f2bf(v);
  } else if (blk < 4096) {
    const int ck = blk - 3328;                   // 768 experts
    const float4* base4 = (const float4*)(Wres + (size_t)ck * 3072);
    float4 v0 = base4[3 * t], v1 = base4[3 * t + 1], v2 = base4[3 * t + 2];
    float vals[12] = {v0.x, v0.y, v0.z, v0.w, v1.x, v1.y, v1.z, v1.w, v2.x, v2.y, v2.z, v2.w};
    float m = 0.f;
#pragma unroll
    for (int i = 0; i < 12; ++i) m = fmaxf(m, fabsf(vals[i]));
    red[t] = m; __syncthreads();
    for (int s = 128; s; s >>= 1) { if (t < s) red[t] = fmaxf(red[t], red[t + s]); __syncthreads(); }
    float mx = fmaxf(red[0], 1e-20f);
    float inv = 127.f / mx;
    if (t == 0) swk[ck] = mx / 127.f;
#pragma unroll
    for (int d = 0; d < 3; ++d) {
      uint32 u = 0;
#pragma unroll
      for (int j = 0; j < 4; ++j)
        u |= ((uint32)(unsigned char)(char)q8(vals[j * 3 + d], inv)) << (8 * j);
      wq[((size_t)(ck * 3 + d) << 8) + t] = u;
    }
  } else {
    const int b = blk - 4096;                    // 16384 rows
    float4 v = ((const float4*)(x + (size_t)b * 1024))[t];
    uint2 o; o.x = pk2(v.x, v.y); o.y = pk2(v.z, v.w);
    xb[(size_t)b * 256 + t] = o;
    float m = fmaxf(fmaxf(fabsf(v.x), fabsf(v.y)), fmaxf(fabsf(v.z), fabsf(v.w)));
    red[t] = m; __syncthreads();
    for (int s = 128; s; s >>= 1) { if (t < s) red[t] = fmaxf(red[t], red[t + s]); __syncthreads(); }
    float mx = fmaxf(red[0], 1e-20f);
    float inv = 127.f / mx;
    if (t == 0) sxb[b] = mx / 127.f;
    uint32 u = ((uint32)(unsigned char)(char)q8(v.x, inv)) |
               ((uint32)(unsigned char)(char)q8(v.y, inv)) << 8 |
               ((uint32)(unsigned char)(char)q8(v.z, inv)) << 16 |
               ((uint32)(unsigned char)(char)q8(v.w, inv)) << 24;
    xq[(size_t)b * 256 + t] = u;
  }
}

// ---------- legacy prep for fallback path ----------
__global__ void prep_wall_f(const float* __restrict__ Wfc, const float* __restrict__ Wbin,
                            ushort16* __restrict__ Wall) {
  int idx = blockIdx.x * 256 + threadIdx.x;
  int j = idx >> 10, n = idx & 1023;
  float v = 0.f;
  if (j < 12) v = Wfc[n * 12 + j];
  else if (j >= 64) v = Wbin[(size_t)(j - 64) * 1024 + n];
  Wall[idx] = f2bf(v);
}
__global__ void prep_wres(const float* __restrict__ Wres, ushort16* __restrict__ Wres_b) {
  int idx = blockIdx.x * 256 + threadIdx.x;
  int n = idx & 1023;
  int d = (idx >> 10) % 3;
  int ck = idx / 3072;
  Wres_b[idx] = f2bf(Wres[((size_t)ck * 1024 + n) * 3 + d]);
}

// ---------- MFMA GEMM + fused per-row argmax/mask epilogue (XB=1) ----------
// BM=128, BN=64 (one group), BK=64; 4 waves 2x2; LDS T2-swizzled, gload_lds staging.
template<int XB>
__global__ __launch_bounds__(256) void gemm_mfma(
    const float* __restrict__ x, const ushort16* __restrict__ xb,
    const float* __restrict__ bfc, const float* __restrict__ bbin,
    const ushort16* __restrict__ Wall, ushort16* __restrict__ ybin,
    unsigned char* __restrict__ ind8, uint64* __restrict__ mask64,
    float* __restrict__ out) {
  __shared__ __align__(16) char smem[24576];     // A: 16384 B, B: 8192 B
  const int t = threadIdx.x;
  const int lane = t & 63, wid = t >> 6;
  const int wm = wid & 1, wn = wid >> 1;

  int orig = blockIdx.x;
  int bid = (orig & 7) * 208 + (orig >> 3);      // XCD-bijective (1664 = 8*208)
  int nb = bid % 13, mb = bid / 13;
  const int b0 = mb * 128;

  f32x4 acc[4][2];
#pragma unroll
  for (int i = 0; i < 4; ++i)
#pragma unroll
    for (int j = 0; j < 2; ++j) acc[i][j] = (f32x4){0.f, 0.f, 0.f, 0.f};

  const int lr = lane & 15, lq = lane >> 4;
  const int fxor = (lr & 7) << 4;
  const int gs = (lane & 7) ^ (lane >> 3);
  const int grw = lane >> 3;

  for (int kc = 0; kc < 1024; kc += 64) {
    __syncthreads();
    if (XB) {
#pragma unroll
      for (int i = 0; i < 4; ++i) {
        int chunk = i * 4 + wid;
        int row = chunk * 8 + grw;
        const ushort16* src = xb + (size_t)(b0 + row) * 1024 + kc + gs * 8;
        __builtin_amdgcn_global_load_lds(
            (const __attribute__((address_space(1))) uint32*)src,
            (__attribute__((address_space(3))) uint32*)(smem + chunk * 1024), 16, 0, 0);
      }
#pragma unroll
      for (int i = 0; i < 2; ++i) {
        int chunk = i * 4 + wid;
        int row = chunk * 8 + grw;
        const ushort16* src = Wall + (size_t)(nb * 64 + row) * 1024 + kc + gs * 8;
        __builtin_amdgcn_global_load_lds(
            (const __attribute__((address_space(1))) uint32*)src,
            (__attribute__((address_space(3))) uint32*)(smem + 16384 + chunk * 1024), 16, 0, 0);
      }
    } else {
      const int sxor = ((t >> 3) & 7) << 4;
#pragma unroll
      for (int i = 0; i < 4; ++i) {
        int s = t + i * 256;
        int row = s >> 3, c8 = (s & 7) * 8;
        int dst = row * 128 + ((c8 * 2) ^ sxor);
        const float4* src = (const float4*)(x + (size_t)(b0 + row) * 1024 + kc + c8);
        float4 v0 = src[0], v1 = src[1];
        u32x4 pv;
        pv.x = pk2(v0.x, v0.y); pv.y = pk2(v0.z, v0.w);
        pv.z = pk2(v1.x, v1.y); pv.w = pk2(v1.z, v1.w);
        *(u32x4*)(smem + dst) = pv;
      }
#pragma unroll
      for (int i = 0; i < 2; ++i) {
        int s = t + i * 256;
        int row = s >> 3, c8 = (s & 7) * 8;
        int dst = 16384 + row * 128 + ((c8 * 2) ^ sxor);
        u32x4 v = *(const u32x4*)(Wall + (size_t)(nb * 64 + row) * 1024 + kc + c8);
        *(u32x4*)(smem + dst) = v;
      }
    }
    __syncthreads();
#pragma unroll
    for (int kk = 0; kk < 2; ++kk) {
      int cbx = (kk * 64 + lq * 16) ^ fxor;
      bf16x8 af[4], bfr[2];
#pragma unroll
      for (int i = 0; i < 4; ++i) {
        int row = wm * 64 + i * 16 + lr;
        af[i] = *(const bf16x8*)(smem + row * 128 + cbx);
      }
#pragma unroll
      for (int j = 0; j < 2; ++j) {
        int row = wn * 32 + j * 16 + lr;
        bfr[j] = *(const bf16x8*)(smem + 16384 + row * 128 + cbx);
      }
#pragma unroll
      for (int i = 0; i < 4; ++i)
#pragma unroll
        for (int j = 0; j < 2; ++j)
          acc[i][j] = __builtin_amdgcn_mfma_f32_16x16x32_bf16(af[i], bfr[j], acc[i][j], 0, 0, 0);
    }
  }

  // ---- epilogue. C/D layout: row=(lane>>4)*4+r, col=lane&15 ----
  if (nb == 0) {
#pragma unroll
    for (int i = 0; i < 4; ++i)
#pragma unroll
      for (int j = 0; j < 2; ++j)
#pragma unroll
        for (int r = 0; r < 4; ++r) {
          int gm = b0 + wm * 64 + i * 16 + lq * 4 + r;
          int col = wn * 32 + j * 16 + lr;
          if (col < 12) out[(size_t)gm * 12 + col] = acc[i][j][r] + bfc[col];
        }
    return;
  }
  const int c = nb - 1;
  if (XB == 0) {
    // fallback: write ybin bf16
#pragma unroll
    for (int i = 0; i < 4; ++i)
#pragma unroll
      for (int j = 0; j < 2; ++j)
#pragma unroll
        for (int r = 0; r < 4; ++r) {
          int gm = b0 + wm * 64 + i * 16 + lq * 4 + r;
          int col = wn * 32 + j * 16 + lr;
          ybin[((size_t)gm * 12 + c) * 64 + col] = f2bf(acc[i][j][r] + bbin[c * 64 + col]);
        }
    return;
  }
  // fused argmax + candidate mask (f32 logits, never materialized)
  __syncthreads();                               // done reading smem tiles
  float* lds_t2 = (float*)smem;                  // [128][2]{m1,m2,k1} = 3072 B
  float* lds_m1 = (float*)(smem + 3072);         // [128] = 512 B
  uint32* lds_ck = (uint32*)(smem + 3584);       // [128][2] = 1024 B
  const float bb0 = bbin[c * 64 + wn * 32 + lr];
  const float bb1 = bbin[c * 64 + wn * 32 + 16 + lr];
  // pass 1: per-row top-2 within this wave's 32 cols (16-lane butterfly)
#pragma unroll
  for (int i = 0; i < 4; ++i)
#pragma unroll
    for (int r = 0; r < 4; ++r) {
      float v0 = acc[i][0][r] + bb0, v1 = acc[i][1][r] + bb1;
      int col0 = wn * 32 + lr;
      float m1, m2; int k1;
      if (v1 > v0) { m1 = v1; k1 = col0 + 16; m2 = v0; }
      else         { m1 = v0; k1 = col0;      m2 = v1; }
#pragma unroll
      for (int off = 1; off < 16; off <<= 1) {
        float om1 = __shfl_xor(m1, off);
        int   ok1 = __shfl_xor(k1, off);
        float om2 = __shfl_xor(m2, off);
        bool take = (om1 > m1) || (om1 == m1 && ok1 < k1);
        float lose = take ? m1 : om1;
        m2 = fmaxf(fmaxf(m2, om2), lose);
        if (take) { m1 = om1; k1 = ok1; }
      }
      if (lr == 0) {
        int row = wm * 64 + i * 16 + lq * 4 + r;
        int e = (row * 2 + wn) * 3;
        lds_t2[e] = m1; lds_t2[e + 1] = m2; lds_t2[e + 2] = __int_as_float(k1);
      }
    }
  __syncthreads();
  // pass 2: cross-wave merge -> ind8, final m1
  if (t < 128) {
    int row = t;
    float a1 = lds_t2[(row * 2) * 3],     a2 = lds_t2[(row * 2) * 3 + 1];
    int   ak = __float_as_int(lds_t2[(row * 2) * 3 + 2]);
    float b1 = lds_t2[(row * 2 + 1) * 3], b2 = lds_t2[(row * 2 + 1) * 3 + 1];
    int   bk = __float_as_int(lds_t2[(row * 2 + 1) * 3 + 2]);
    float m1, m2; int k1;
    if (b1 > a1 || (b1 == a1 && bk < ak)) { m1 = b1; k1 = bk; m2 = fmaxf(a1, b2); }
    else                                  { m1 = a1; k1 = ak; m2 = fmaxf(b1, a2); }
    ind8[(b0 + row) * 12 + c] = (unsigned char)(k1 | ((m1 - m2 <= MARGIN) ? 128 : 0));
    lds_m1[row] = m1;
  }
  __syncthreads();
  // pass 3: candidate-mask ballots against final m1
#pragma unroll
  for (int i = 0; i < 4; ++i)
#pragma unroll
    for (int r = 0; r < 4; ++r) {
      int row = wm * 64 + i * 16 + lq * 4 + r;
      float thr = lds_m1[row] - MARGIN;
      uint64 bal0 = __ballot(acc[i][0][r] + bb0 >= thr);
      uint64 bal1 = __ballot(acc[i][1][r] + bb1 >= thr);
      if (lr == 0) {
        uint32 chunk = (uint32)((bal0 >> (lq * 16)) & 0xffffull) |
                       ((uint32)((bal1 >> (lq * 16)) & 0xffffull) << 16);
        lds_ck[row * 2 + wn] = chunk;
      }
    }
  __syncthreads();
  if (t < 128) {
    int row = t;
    uint64 mk = (uint64)lds_ck[row * 2] | ((uint64)lds_ck[row * 2 + 1] << 32);
    mask64[(b0 + row) * 12 + c] = mk;
  }
}

// ---------- B: per-b block, 3 classes/wave interleaved, int8 dot ----------
__global__ __launch_bounds__(256) void gather_k(
    const uint32* __restrict__ xq, const float* __restrict__ sxb,
    const unsigned char* __restrict__ ind8, const uint32* __restrict__ wq,
    const float* __restrict__ swk, const float* __restrict__ bres,
    const float* __restrict__ centers, float* __restrict__ out) {
  const int lane = threadIdx.x & 63;
  const int w = threadIdx.x >> 6;
  const int b = blockIdx.x;

  const u32x4 xi = *(const u32x4*)(xq + (size_t)b * 256 + lane * 4);
  const float sx = sxb[b];
  const size_t obase = (size_t)B_SZ * 12 + (size_t)b * 36;

  int ind[3], ck[3];
  u32x4 wv[3][3];
#pragma unroll
  for (int cc = 0; cc < 3; ++cc) {
    int c = w * 3 + cc;
    ind[cc] = ind8[b * 12 + c] & 63;
    ck[cc] = c * 64 + ind[cc];
    const uint32* wr = wq + (size_t)ck[cc] * 768;
#pragma unroll
    for (int d = 0; d < 3; ++d)
      wv[cc][d] = *(const u32x4*)(wr + d * 256 + lane * 4);
  }
  int acc[3][3];
#pragma unroll
  for (int cc = 0; cc < 3; ++cc)
#pragma unroll
    for (int d = 0; d < 3; ++d) {
      int s = dot4(xi.x, wv[cc][d].x, 0);
      s = dot4(xi.y, wv[cc][d].y, s);
      s = dot4(xi.z, wv[cc][d].z, s);
      acc[cc][d] = dot4(xi.w, wv[cc][d].w, s);
    }
  for (int off = 32; off; off >>= 1) {
#pragma unroll
    for (int cc = 0; cc < 3; ++cc)
#pragma unroll
      for (int d = 0; d < 3; ++d)
        acc[cc][d] += __shfl_xor(acc[cc][d], off);
  }
  if (lane == 0) {
#pragma unroll
    for (int cc = 0; cc < 3; ++cc) {
      int c = w * 3 + cc;
      float sc = sx * swk[ck[cc]];
      out[obase + 0 * 12 + c] = centers[ind[cc] * 3 + 0] + bres[ck[cc] * 3 + 0] + sc * (float)acc[cc][0];
      out[obase + 1 * 12 + c] = centers[ind[cc] * 3 + 1] + bres[ck[cc] * 3 + 1] + sc * (float)acc[cc][1];
      out[obase + 2 * 12 + c] = centers[ind[cc] * 3 + 2] + bres[ck[cc] * 3 + 2] + sc * (float)acc[cc][2];
    }
  }
}

// ---------- C: one wave per pair; f64 rescue using precomputed mask ----------
__global__ __launch_bounds__(256) void rescue2(
    const float* __restrict__ x, const float* __restrict__ Wbin,
    const float* __restrict__ bbin, const float* __restrict__ bres,
    const float* __restrict__ centers, const unsigned char* __restrict__ ind8,
    const uint64* __restrict__ mask64, const uint32* __restrict__ wq,
    const float* __restrict__ swk, const uint32* __restrict__ xq,
    const float* __restrict__ sxb, float* __restrict__ out) {
  const int lane = threadIdx.x & 63;
  const int w = threadIdx.x >> 6;
  const int p = blockIdx.x * 4 + w;              // 49152 blocks -> 196608 pairs
  const int iv = ind8[p];
  if (!(iv & 128)) return;                       // wave-uniform
  const int b = p / 12, c = p % 12;
  uint64 mask = mask64[p];
  float xv[16];
  const float4* xr = (const float4*)(x + (size_t)b * 1024 + lane * 16);
#pragma unroll
  for (int q = 0; q < 4; ++q) {
    float4 vv = xr[q];
    xv[4 * q] = vv.x; xv[4 * q + 1] = vv.y; xv[4 * q + 2] = vv.z; xv[4 * q + 3] = vv.w;
  }
  double best = -1.0e300;
  int bk = 0;
  while (mask) {
    int k = __ffsll(mask) - 1;
    mask &= (mask - 1);
    const float4* wr4 = (const float4*)(Wbin + ((size_t)c * 64 + k) * 1024 + lane * 16);
    double s = 0.0;
#pragma unroll
    for (int q = 0; q < 4; ++q) {
      float4 wvv = wr4[q];
      s += (double)xv[4 * q] * (double)wvv.x + (double)xv[4 * q + 1] * (double)wvv.y +
           (double)xv[4 * q + 2] * (double)wvv.z + (double)xv[4 * q + 3] * (double)wvv.w;
    }
    for (int off = 32; off; off >>= 1) s += __shfl_xor(s, off);
    s += (double)bbin[c * 64 + k];
    if (s > best) { best = s; bk = k; }          // ascending k + strict > = first-max
  }
  if (bk != (iv & 63)) {                         // flipped: recompute the 3 outputs
    const u32x4 xi = *(const u32x4*)(xq + (size_t)b * 256 + lane * 4);
    const int ckk = c * 64 + bk;
    const uint32* wr = wq + (size_t)ckk * 768;
    int acc[3];
#pragma unroll
    for (int d = 0; d < 3; ++d) {
      u32x4 wvq = *(const u32x4*)(wr + d * 256 + lane * 4);
      int s = dot4(xi.x, wvq.x, 0);
      s = dot4(xi.y, wvq.y, s);
      s = dot4(xi.z, wvq.z, s);
      acc[d] = dot4(xi.w, wvq.w, s);
    }
    for (int off = 32; off; off >>= 1) {
      acc[0] += __shfl_xor(acc[0], off);
      acc[1] += __shfl_xor(acc[1], off);
      acc[2] += __shfl_xor(acc[2], off);
    }
    if (lane == 0) {
      const size_t obase = (size_t)B_SZ * 12 + (size_t)b * 36;
      float sc = sxb[b] * swk[ckk];
      out[obase + 0 * 12 + c] = centers[bk * 3 + 0] + bres[ckk * 3 + 0] + sc * (float)acc[0];
      out[obase + 1 * 12 + c] = centers[bk * 3 + 1] + bres[ckk * 3 + 1] + sc * (float)acc[1];
      out[obase + 2 * 12 + c] = centers[bk * 3 + 2] + bres[ckk * 3 + 2] + sc * (float)acc[2];
    }
  }
}

// ---------- fallback select (R3-validated, bf16 Wres_b, f32 x, reads ybin) ----------
__global__ __launch_bounds__(256) void select2(
    const float* __restrict__ x, const float* __restrict__ Wbin,
    const float* __restrict__ bbin, const float* __restrict__ bres,
    const float* __restrict__ centers, const ushort16* __restrict__ Wres_b,
    const ushort16* __restrict__ ybin, float* __restrict__ out) {
  const int lane = threadIdx.x & 63;
  const int w = threadIdx.x >> 6;
  const int b = blockIdx.x;
  float xv[16];
  {
    const float4* xr = (const float4*)(x + (size_t)b * 1024 + lane * 16);
#pragma unroll
    for (int q = 0; q < 4; ++q) {
      float4 v = xr[q];
      xv[4 * q] = v.x; xv[4 * q + 1] = v.y; xv[4 * q + 2] = v.z; xv[4 * q + 3] = v.w;
    }
  }
  const size_t obase = (size_t)B_SZ * 12 + (size_t)b * 36;
#pragma unroll 1
  for (int cc = 0; cc < 3; ++cc) {
    const int c = w * 3 + cc;
    float v = bf2f(ybin[((size_t)b * 12 + c) * 64 + lane]);
    float m1 = v, m2 = -3.4e38f;
    int k1 = lane;
    for (int off = 32; off; off >>= 1) {
      float om1 = __shfl_xor(m1, off);
      int   ok1 = __shfl_xor(k1, off);
      float om2 = __shfl_xor(m2, off);
      bool take = (om1 > m1) || (om1 == m1 && ok1 < k1);
      float lose = take ? m1 : om1;
      m2 = fmaxf(fmaxf(m2, om2), lose);
      if (take) { m1 = om1; k1 = ok1; }
    }
    int ind = k1;
    if (m1 - m2 <= MARGIN) {
      unsigned long long mask = __ballot(v >= m1 - MARGIN);
      double best = -1.0e300;
      int bk = 0;
      while (mask) {
        int k = __ffsll(mask) - 1;
        mask &= (mask - 1);
        const float4* wr4 = (const float4*)(Wbin + ((size_t)c * 64 + k) * 1024 + lane * 16);
        double s = 0.0;
#pragma unroll
        for (int q = 0; q < 4; ++q) {
          float4 wv = wr4[q];
          s += (double)xv[4 * q] * (double)wv.x + (double)xv[4 * q + 1] * (double)wv.y +
               (double)xv[4 * q + 2] * (double)wv.z + (double)xv[4 * q + 3] * (double)wv.w;
        }
        for (int off = 32; off; off >>= 1) s += __shfl_xor(s, off);
        s += (double)bbin[c * 64 + k];
        if (s > best) { best = s; bk = k; }
      }
      ind = bk;
    }
    const ushort16* wr = Wres_b + ((size_t)(c * 64 + ind) * 3) * 1024;
    float a[3] = {0.f, 0.f, 0.f};
#pragma unroll
    for (int d = 0; d < 3; ++d) {
      const u32x4* pp = (const u32x4*)(wr + d * 1024 + lane * 16);
      u32x4 w0 = pp[0], w1 = pp[1];
      uint32 uw[8] = {w0.x, w0.y, w0.z, w0.w, w1.x, w1.y, w1.z, w1.w};
#pragma unroll
      for (int q = 0; q < 8; ++q) {
        a[d] = fmaf(xv[2 * q],     bflo(uw[q]), a[d]);
        a[d] = fmaf(xv[2 * q + 1], bfhi(uw[q]), a[d]);
      }
    }
    for (int off = 32; off; off >>= 1) {
      a[0] += __shfl_xor(a[0], off);
      a[1] += __shfl_xor(a[1], off);
      a[2] += __shfl_xor(a[2], off);
    }
    if (lane == 0) {
      int ck = c * 64 + ind;
      out[obase + 0 * 12 + c] = centers[ind * 3 + 0] + bres[ck * 3 + 0] + a[0];
      out[obase + 1 * 12 + c] = centers[ind * 3 + 1] + bres[ck * 3 + 1] + a[1];
      out[obase + 2 * 12 + c] = centers[ind * 3 + 2] + bres[ck * 3 + 2] + a[2];
    }
  }
}

extern "C" void kernel_launch(void* const* d_in, const int* in_sizes, int n_in,
                              void* d_out, int out_size, void* d_ws, size_t ws_size,
                              hipStream_t stream) {
  const float* x       = (const float*)d_in[0];
  const float* Wfc     = (const float*)d_in[1];
  const float* bfc     = (const float*)d_in[2];
  const float* Wbin    = (const float*)d_in[3];
  const float* bbin    = (const float*)d_in[4];
  const float* Wres    = (const float*)d_in[5];
  const float* bres    = (const float*)d_in[6];
  const float* centers = (const float*)d_in[7];
  float* out = (float*)d_out;

  char* ws = (char*)d_ws;
  ushort16* Wall = (ushort16*)ws;                              // 1,703,936 B
  if (ws_size >= 56232960ull) {
    uint32*        wq     = (uint32*)(ws + 1703936);           // 2,359,296 B
    float*         swk    = (float*)(ws + 4063232);            // 3,072 B
    unsigned char* ind8   = (unsigned char*)(ws + 4066304);    // 196,608 B
    uint64*        mask64 = (uint64*)(ws + 4262912);           // 1,572,864 B
    ushort16*      xb     = (ushort16*)(ws + 5835776);         // 33,554,432 B
    uint32*        xq     = (uint32*)(ws + 39390208);          // 16,777,216 B
    float*         sxb    = (float*)(ws + 56167424);           // 65,536 B -> end 56,232,960

    prep_all<<<20480, 256, 0, stream>>>(Wfc, Wbin, Wres, x, Wall, wq, swk,
                                        (uint2*)xb, xq, sxb);
    gemm_mfma<1><<<1664, 256, 0, stream>>>(x, xb, bfc, bbin, Wall,
                                           (ushort16*)nullptr, ind8, mask64, out);
    gather_k<<<B_SZ, 256, 0, stream>>>(xq, sxb, ind8, wq, swk, bres, centers, out);
    rescue2<<<49152, 256, 0, stream>>>(x, Wbin, bbin, bres, centers, ind8, mask64,
                                       wq, swk, xq, sxb, out);
  } else {
    // fallback: bf16 select path (no ind8/mask; gemm writes ybin)
    ushort16* Wres_b = (ushort16*)(ws + 1703936);              // 4,718,592 B
    ushort16* ybin   = (ushort16*)(ws + 6422528);              // 25,165,824 B
    prep_wall_f<<<3328, 256, 0, stream>>>(Wfc, Wbin, Wall);
    prep_wres<<<9216, 256, 0, stream>>>(Wres, Wres_b);
    gemm_mfma<0><<<1664, 256, 0, stream>>>(x, (const ushort16*)ws, bfc, bbin, Wall,
                                           ybin, (unsigned char*)nullptr,
                                           (uint64*)nullptr, out);
    select2<<<B_SZ, 256, 0, stream>>>(x, Wbin, bbin, bres, centers, Wres_b, ybin, out);
  }
}